// Round 1
// baseline (193.199 us; speedup 1.0000x reference)
//
#include <hip/hip_runtime.h>

#define NUM_FIELDS 32
#define EMBED_DIM  64
#define NUM_PAIRS  496   // 32*31/2

// Compile-time pair index table, identical order to the Python reference:
// [(i,j) for i in range(F-1) for j in range(i+1, F)]
struct Pairs {
    unsigned char r[NUM_PAIRS];
    unsigned char c[NUM_PAIRS];
};
constexpr Pairs make_pairs() {
    Pairs t{};
    int p = 0;
    for (int i = 0; i < NUM_FIELDS - 1; ++i)
        for (int j = i + 1; j < NUM_FIELDS; ++j) {
            t.r[p] = (unsigned char)i;
            t.c[p] = (unsigned char)j;
            ++p;
        }
    return t;
}
__device__ constexpr Pairs PAIRS = make_pairs();

// One block of 256 threads per batch row.
//  - 512 float4s per row (32 fields x 16 float4s). Thread t loads x4[t] and
//    x4[256+t]; each float4 lies entirely within one field (field = t/16 and
//    16 + t/16 respectively), so a 16-lane shfl_xor butterfly yields the
//    per-field sum. Lane t%16==0 publishes s[f] to LDS.
//  - Epilogue: 496 products = 124 float4 stores; threads 0..123 each compute
//    4 pair products from LDS (mostly-broadcast reads) and store one float4.
__global__ __launch_bounds__(256)
void opn_kernel(const float* __restrict__ x, float* __restrict__ out, int batch) {
    const int b = blockIdx.x;
    if (b >= batch) return;
    const int t = threadIdx.x;

    __shared__ float s_sh[NUM_FIELDS];

    const float4* __restrict__ x4 =
        (const float4*)(x + (size_t)b * NUM_FIELDS * EMBED_DIM);

    float4 a = x4[t];
    float4 c = x4[256 + t];
    float p1 = (a.x + a.y) + (a.z + a.w);
    float p2 = (c.x + c.y) + (c.z + c.w);

    // Reduce across the 16 lanes sharing a field (xor masks < 16 stay in-group).
    #pragma unroll
    for (int off = 8; off >= 1; off >>= 1) {
        p1 += __shfl_xor(p1, off);
        p2 += __shfl_xor(p2, off);
    }

    if ((t & 15) == 0) {
        const int f = t >> 4;          // 0..15
        s_sh[f]      = p1;             // fields 0..15
        s_sh[16 + f] = p2;             // fields 16..31
    }
    __syncthreads();

    if (t < NUM_PAIRS / 4) {           // 124 threads
        const int p0 = t * 4;
        float4 r;
        r.x = s_sh[PAIRS.r[p0 + 0]] * s_sh[PAIRS.c[p0 + 0]];
        r.y = s_sh[PAIRS.r[p0 + 1]] * s_sh[PAIRS.c[p0 + 1]];
        r.z = s_sh[PAIRS.r[p0 + 2]] * s_sh[PAIRS.c[p0 + 2]];
        r.w = s_sh[PAIRS.r[p0 + 3]] * s_sh[PAIRS.c[p0 + 3]];
        // 496 floats = 1984 bytes per row -> every row is 16B-aligned.
        ((float4*)(out + (size_t)b * NUM_PAIRS))[t] = r;
    }
}

extern "C" void kernel_launch(void* const* d_in, const int* in_sizes, int n_in,
                              void* d_out, int out_size, void* d_ws, size_t ws_size,
                              hipStream_t stream) {
    const float* x = (const float*)d_in[0];
    float* out = (float*)d_out;
    const int batch = in_sizes[0] / (NUM_FIELDS * EMBED_DIM);  // 16384
    opn_kernel<<<batch, 256, 0, stream>>>(x, out, batch);
}

// Round 3
// 189.253 us; speedup vs baseline: 1.0208x; 1.0208x over previous
//
#include <hip/hip_runtime.h>

#define NUM_FIELDS 32
#define EMBED_DIM  64
#define NUM_PAIRS  496   // 32*31/2
#define ROWS       8     // batch rows per block
#define P4         (NUM_PAIRS / 4)   // 124 float4 outputs per row

// Native vector type: __builtin_nontemporal_* requires scalar/vector-of-scalar
// pointee, not HIP_vector_type (a struct).
typedef float f4 __attribute__((ext_vector_type(4)));

// Compile-time pair index table, identical order to the Python reference:
// [(i,j) for i in range(F-1) for j in range(i+1, F)]
struct Pairs {
    unsigned char r[NUM_PAIRS];
    unsigned char c[NUM_PAIRS];
};
constexpr Pairs make_pairs() {
    Pairs t{};
    int p = 0;
    for (int i = 0; i < NUM_FIELDS - 1; ++i)
        for (int j = i + 1; j < NUM_FIELDS; ++j) {
            t.r[p] = (unsigned char)i;
            t.c[p] = (unsigned char)j;
            ++p;
        }
    return t;
}
__device__ constexpr Pairs PAIRS = make_pairs();

// 256 threads, ROWS=8 batch rows per block (grid = 2048 blocks).
//  Phase 1: issue all 16 nontemporal f4 loads (8 rows x 2 per thread) —
//           high memory-level parallelism; each f4 lies inside one field.
//  Phase 2: per row, 16-lane shfl_xor butterfly -> per-field sums -> LDS.
//  Phase 3: one __syncthreads, then 8*124=992 f4 product stores, fully
//           contiguous across the 8-row output span, all 256 threads busy.
__global__ __launch_bounds__(256)
void opn_kernel(const float* __restrict__ x, float* __restrict__ out, int batch) {
    const int t = threadIdx.x;
    const int row0 = blockIdx.x * ROWS;
    if (row0 >= batch) return;

    __shared__ float s_sh[ROWS][NUM_FIELDS];

    const f4* __restrict__ x4 =
        (const f4*)(x + (size_t)row0 * NUM_FIELDS * EMBED_DIM);

    // Phase 1: all loads up front (512 f4 per row; thread t takes t and 256+t).
    f4 a[ROWS], c[ROWS];
    #pragma unroll
    for (int r = 0; r < ROWS; ++r) {
        a[r] = __builtin_nontemporal_load(&x4[r * 512 + t]);
        c[r] = __builtin_nontemporal_load(&x4[r * 512 + 256 + t]);
    }

    // Phase 2: horizontal add + 16-lane butterfly (xor masks < 16 stay in-group).
    #pragma unroll
    for (int r = 0; r < ROWS; ++r) {
        float p1 = (a[r].x + a[r].y) + (a[r].z + a[r].w);
        float p2 = (c[r].x + c[r].y) + (c[r].z + c[r].w);
        #pragma unroll
        for (int off = 8; off >= 1; off >>= 1) {
            p1 += __shfl_xor(p1, off);
            p2 += __shfl_xor(p2, off);
        }
        if ((t & 15) == 0) {
            const int f = t >> 4;          // 0..15
            s_sh[r][f]      = p1;          // fields 0..15
            s_sh[r][16 + f] = p2;          // fields 16..31
        }
    }
    __syncthreads();

    // Phase 3: 992 f4 stores; flat index i = r*124 + q maps directly to
    // f4 offset i within the contiguous 8-row output span (496/4 == 124).
    f4* __restrict__ o4 = (f4*)(out + (size_t)row0 * NUM_PAIRS);
    #pragma unroll
    for (int i = t; i < ROWS * P4; i += 256) {
        const int r  = i / P4;
        const int p0 = (i - r * P4) * 4;
        f4 v;
        v.x = s_sh[r][PAIRS.r[p0 + 0]] * s_sh[r][PAIRS.c[p0 + 0]];
        v.y = s_sh[r][PAIRS.r[p0 + 1]] * s_sh[r][PAIRS.c[p0 + 1]];
        v.z = s_sh[r][PAIRS.r[p0 + 2]] * s_sh[r][PAIRS.c[p0 + 2]];
        v.w = s_sh[r][PAIRS.r[p0 + 3]] * s_sh[r][PAIRS.c[p0 + 3]];
        __builtin_nontemporal_store(v, &o4[i]);
    }
}

extern "C" void kernel_launch(void* const* d_in, const int* in_sizes, int n_in,
                              void* d_out, int out_size, void* d_ws, size_t ws_size,
                              hipStream_t stream) {
    const float* x = (const float*)d_in[0];
    float* out = (float*)d_out;
    const int batch = in_sizes[0] / (NUM_FIELDS * EMBED_DIM);  // 16384
    const int grid = (batch + ROWS - 1) / ROWS;                // 2048
    opn_kernel<<<grid, 256, 0, stream>>>(x, out, batch);
}

// Round 4
// 188.302 us; speedup vs baseline: 1.0260x; 1.0051x over previous
//
#include <hip/hip_runtime.h>

#define NUM_FIELDS 32
#define EMBED_DIM  64
#define NUM_PAIRS  496   // 32*31/2
#define P4         (NUM_PAIRS / 4)   // 124 float4 outputs per row
#define WAVES      8     // one batch row per wave; block = 512 threads

// Native vector type: __builtin_nontemporal_* requires scalar/vector-of-scalar
// pointee, not HIP_vector_type (a struct).
typedef float f4 __attribute__((ext_vector_type(4)));

// Compile-time pair index table, identical order to the Python reference:
// [(i,j) for i in range(F-1) for j in range(i+1, F)]
struct Pairs {
    unsigned char r[NUM_PAIRS];
    unsigned char c[NUM_PAIRS];
};
constexpr Pairs make_pairs() {
    Pairs t{};
    int p = 0;
    for (int i = 0; i < NUM_FIELDS - 1; ++i)
        for (int j = i + 1; j < NUM_FIELDS; ++j) {
            t.r[p] = (unsigned char)i;
            t.c[p] = (unsigned char)j;
            ++p;
        }
    return t;
}
__device__ constexpr Pairs PAIRS = make_pairs();

// One batch row per WAVE (wave-decoupled: no __syncthreads anywhere).
//  Loads:  row = 512 f4s; lane loads f4[k*64+lane], k=0..7 — each instruction
//          covers a contiguous 1 KiB span (perfect coalescing). f4 #(k*64+lane)
//          lies in field 4k + lane/16.
//  Reduce: hsum each f4, then one 16-lane shfl_xor butterfly over all 8
//          partials. After it, every lane in group g (=lane/16) holds
//          s[4k+g] for k=0..7. Lane (lane%16)==0 of each group writes its 8
//          sums to the wave-private LDS slice (static p[k] indices, distinct
//          banks 4k+g).
//  Epilogue: same wave reads the 32 sums back (lgkmcnt dependency only — no
//          barrier needed within a wave) and stores 124 f4 products.
__global__ __launch_bounds__(WAVES * 64)
void opn_kernel(const float* __restrict__ x, float* __restrict__ out, int batch) {
    const int wave = threadIdx.x >> 6;   // 0..7
    const int lane = threadIdx.x & 63;
    const int row  = blockIdx.x * WAVES + wave;
    if (row >= batch) return;

    __shared__ float s_sh[WAVES][NUM_FIELDS];

    const f4* __restrict__ x4 =
        (const f4*)(x + (size_t)row * NUM_FIELDS * EMBED_DIM);

    // All 8 loads issued up front (independent -> 8 outstanding per lane).
    f4 v[8];
    #pragma unroll
    for (int k = 0; k < 8; ++k)
        v[k] = __builtin_nontemporal_load(&x4[k * 64 + lane]);

    float p[8];
    #pragma unroll
    for (int k = 0; k < 8; ++k)
        p[k] = (v[k].x + v[k].y) + (v[k].z + v[k].w);

    // 16-lane butterfly (xor masks < 16 stay inside the group of 16).
    #pragma unroll
    for (int off = 8; off >= 1; off >>= 1) {
        #pragma unroll
        for (int k = 0; k < 8; ++k)
            p[k] += __shfl_xor(p[k], off);
    }

    const int g = lane >> 4;             // group 0..3
    if ((lane & 15) == 0) {
        #pragma unroll
        for (int k = 0; k < 8; ++k)      // static register indices
            s_sh[wave][4 * k + g] = p[k];
    }
    // Same-wave LDS write->read: compiler-inserted s_waitcnt lgkmcnt(0)
    // provides ordering; no __syncthreads required (wave-private slice).

    f4* __restrict__ o4 = (f4*)(out + (size_t)row * NUM_PAIRS);
    #pragma unroll
    for (int rep = 0; rep < 2; ++rep) {
        const int i = rep * 64 + lane;
        if (i < P4) {
            const int p0 = i * 4;
            f4 r;
            r.x = s_sh[wave][PAIRS.r[p0 + 0]] * s_sh[wave][PAIRS.c[p0 + 0]];
            r.y = s_sh[wave][PAIRS.r[p0 + 1]] * s_sh[wave][PAIRS.c[p0 + 1]];
            r.z = s_sh[wave][PAIRS.r[p0 + 2]] * s_sh[wave][PAIRS.c[p0 + 2]];
            r.w = s_sh[wave][PAIRS.r[p0 + 3]] * s_sh[wave][PAIRS.c[p0 + 3]];
            __builtin_nontemporal_store(r, &o4[i]);
        }
    }
}

extern "C" void kernel_launch(void* const* d_in, const int* in_sizes, int n_in,
                              void* d_out, int out_size, void* d_ws, size_t ws_size,
                              hipStream_t stream) {
    const float* x = (const float*)d_in[0];
    float* out = (float*)d_out;
    const int batch = in_sizes[0] / (NUM_FIELDS * EMBED_DIM);  // 16384
    const int grid = (batch + WAVES - 1) / WAVES;              // 2048
    opn_kernel<<<grid, WAVES * 64, 0, stream>>>(x, out, batch);
}